// Round 9
// baseline (215.909 us; speedup 1.0000x reference)
//
#include <hip/hip_runtime.h>

#define N_SPIKES 16384
#define N_UNITS  256
#define N_NEIGHB 128
#define RANK     5
#define NC       64
#define NC_OBS   12
#define N_CAND   10
#define DD       60                 // RANK * NC_OBS
#define DD4      15                 // DD / 4
#define WPAD     64                 // padded w row: 60 w + b + 3 zero
#define OUT_COLS 61
#define OUT_SIZE (N_UNITS * OUT_COLS)   // 15616
#define S_BLOCKS 128

__device__ __forceinline__ void atom_add(float* p, float v) {
    unsafeAtomicAdd(p, v);
}

// ---------------------------------------------------------------------------
// Kernel P: fused nu-gather + matvec.  Lane owns unit.
//   w64[p][0:60] = Coo_inv[h] @ nu ;  w64[p][60] = log_prop[u] - 0.5 nu.w ;
//   w64[p][61:64] = 0.   Row = 256 B aligned -> a 16-lane float4 gather of
//   one row is exactly 4 cache lines and carries the bias for free.
// ---------------------------------------------------------------------------
__global__ __launch_bounds__(128) void precompute_kernel(
    const float* __restrict__ mu, const float* __restrict__ Coo_inv,
    const int* __restrict__ obs_ix, const float* __restrict__ log_prop,
    float* __restrict__ w64)
{
    __shared__ float tile[128 * 61];

    const int h    = blockIdx.x >> 1;
    const int tid  = threadIdx.x;
    const int lane = tid & 63;
    const int wave = tid >> 6;
    const int u    = (blockIdx.x & 1) * 128 + wave * 64 + lane;
    const int p    = h * N_UNITS + u;

    int so[NC_OBS];
#pragma unroll
    for (int j = 0; j < NC_OBS; ++j) so[j] = obs_ix[h * NC_OBS + j];

    const float* __restrict__ mub = mu + u * (RANK * NC);
    float* tl = &tile[tid * 61];
#pragma unroll
    for (int d = 0; d < DD; ++d) {
        const int r = d / NC_OBS;
        const int j = d - r * NC_OBS;
        tl[d] = mub[r * NC + so[j]];
    }

    float wreg[DD];
#pragma unroll
    for (int d = 0; d < DD; ++d) wreg[d] = 0.f;

    const float* __restrict__ C = Coo_inv + h * DD * DD;
    for (int e = 0; e < DD; ++e) {
        const float nu_e = tl[e];
        const float* __restrict__ Crow = C + e * DD;
#pragma unroll
        for (int d = 0; d < DD; ++d)
            wreg[d] = fmaf(Crow[d], nu_e, wreg[d]);
    }

    float q2 = 0.f;
#pragma unroll
    for (int d = 0; d < DD; ++d) q2 += wreg[d] * tl[d];

    float4* __restrict__ wout = (float4*)(w64 + (size_t)p * WPAD);
#pragma unroll
    for (int k = 0; k < DD4; ++k) {
        float4 o;
        o.x = wreg[4*k+0]; o.y = wreg[4*k+1];
        o.z = wreg[4*k+2]; o.w = wreg[4*k+3];
        wout[k] = o;
    }
    float4 tail;
    tail.x = log_prop[u] - 0.5f * q2;   // bias in slot 60
    tail.y = 0.f; tail.z = 0.f; tail.w = 0.f;
    wout[DD4] = tail;
}

// ---------------------------------------------------------------------------
// Kernel Q: per-spike posterior q[n][c].  ZERO LDS -> 16 waves/CU across
// 4 independent blocks (1024 blocks x 256 thr, 16-lane group per spike).
// Lane 15 of each group carries the bias: xf_15 = (1,0,0,0), so the
// 16-lane xor-sum of dot4 yields  b + w.xf  in one tree.
// ---------------------------------------------------------------------------
__global__ __launch_bounds__(256, 4) void q_kernel(
    const float* __restrict__ features, const float* __restrict__ noise_lp,
    const int* __restrict__ cands, const int* __restrict__ nid,
    const float* __restrict__ w64, float* __restrict__ q_buf)
{
    const int tid = threadIdx.x;
    const int l   = tid & 15;
    const int n   = blockIdx.x * 16 + (tid >> 4);
    const bool dimlane = (l < DD4);

    const float4* __restrict__ f4 = (const float4*)features;
    const float4* __restrict__ w4 = (const float4*)w64;
    const float nlp = noise_lp[0];

    float4 xf;
    if (dimlane) xf = f4[n * DD4 + l];
    else { xf.x = 1.f; xf.y = 0.f; xf.z = 0.f; xf.w = 0.f; }

    const int h = nid[n];
    int uc[N_CAND];
#pragma unroll
    for (int c = 0; c < N_CAND; ++c) uc[c] = cands[n * N_CAND + c];

    float4 wv[N_CAND];
#pragma unroll
    for (int c = 0; c < N_CAND; ++c)
        wv[c] = w4[(size_t)(h * N_UNITS + uc[c]) * (WPAD / 4) + l];

    float ll[N_CAND];
#pragma unroll
    for (int c = 0; c < N_CAND; ++c) {
        float t = wv[c].x*xf.x + wv[c].y*xf.y + wv[c].z*xf.z + wv[c].w*xf.w;
        t += __shfl_xor(t, 8, 64);
        t += __shfl_xor(t, 4, 64);
        t += __shfl_xor(t, 2, 64);
        t += __shfl_xor(t, 1, 64);
        ll[c] = t;                     // = b + w.xf  (bias via lane 15)
    }

    float m = nlp;
#pragma unroll
    for (int c = 0; c < N_CAND; ++c) m = fmaxf(m, ll[c]);
    float z = __expf(nlp - m);
    float qv[N_CAND];
#pragma unroll
    for (int c = 0; c < N_CAND; ++c) { qv[c] = __expf(ll[c] - m); z += qv[c]; }
    const float inv = 1.f / z;

    float myq = 0.f;
#pragma unroll
    for (int c = 0; c < N_CAND; ++c) myq = (l == c) ? qv[c] * inv : myq;
    if (l < N_CAND) q_buf[n * N_CAND + l] = myq;
}

// ---------------------------------------------------------------------------
// Kernel S: scatter-only.  128 blocks x 512 thr; block owns 128 spikes,
// wave owns 16.  Streams q/cands/features (no gathers), accumulates via
// native ds_add into the LDS table, flushes with plain stores to partials.
// ---------------------------------------------------------------------------
__global__ __launch_bounds__(512, 2) void scatter_kernel(
    const float* __restrict__ features, const float* __restrict__ q_buf,
    const int* __restrict__ cands, float* __restrict__ partials)
{
    __shared__ float acc[OUT_SIZE];
    const int tid = threadIdx.x;
    for (int i = tid; i < OUT_SIZE; i += 512) acc[i] = 0.f;
    __syncthreads();

    const int lane = tid & 63;
    const int wave = tid >> 6;
    const int dl   = (lane < DD) ? lane : 0;

    for (int i = 0; i < 16; ++i) {
        const int sp = blockIdx.x * 128 + wave * 16 + i;
        const float xf  = features[sp * DD + dl];
        const float val = (lane < DD) ? xf : 1.f;
#pragma unroll
        for (int c = 0; c < N_CAND; ++c) {
            const float qq = q_buf[sp * N_CAND + c];   // wave-uniform
            const int  uu = cands[sp * N_CAND + c];    // wave-uniform
            if (lane <= DD) {
                const int addr = (lane < DD) ? (uu * OUT_COLS + 1 + lane)
                                             : (uu * OUT_COLS);
                atom_add(&acc[addr], qq * val);
            }
        }
    }

    __syncthreads();
    float* __restrict__ pb = partials + (size_t)blockIdx.x * OUT_SIZE;
    for (int i = tid; i < OUT_SIZE; i += 512) pb[i] = acc[i];
}

// ---------------------------------------------------------------------------
// Kernel R: sum 128 partials -> d_out.  61 blocks x 256 thr.
// ---------------------------------------------------------------------------
__global__ __launch_bounds__(256) void reduce_kernel(
    const float* __restrict__ partials, float* __restrict__ out)
{
    const int i = blockIdx.x * 256 + threadIdx.x;
    float s = 0.f;
#pragma unroll 8
    for (int b = 0; b < S_BLOCKS; ++b)
        s += partials[(size_t)b * OUT_SIZE + i];
    out[i] = s;
}

extern "C" void kernel_launch(void* const* d_in, const int* in_sizes, int n_in,
                              void* d_out, int out_size, void* d_ws, size_t ws_size,
                              hipStream_t stream) {
    const float* features    = (const float*)d_in[0];
    const float* mu          = (const float*)d_in[1];
    const float* Coo_inv     = (const float*)d_in[2];
    // d_in[3] = Coo_logdet : unused (cancels in softmax)
    const float* log_prop    = (const float*)d_in[4];
    const float* noise_lp    = (const float*)d_in[5];
    const int*   cands       = (const int*)d_in[6];
    const int*   nid         = (const int*)d_in[7];
    const int*   obs_ix      = (const int*)d_in[8];
    float* out = (float*)d_out;

    char* ws = (char*)d_ws;
    float* w64      = (float*)ws;                          // 128*256*64*4 = 8,388,608 B
    float* q_buf    = (float*)(ws + 8388608);              // 16384*10*4   =   655,360 B
    float* partials = (float*)(ws + 8388608 + 655360);     // 128*15616*4  = 7,995,392 B
                                                           // total ~17.0 MB

    precompute_kernel<<<256, 128, 0, stream>>>(mu, Coo_inv, obs_ix, log_prop, w64);
    q_kernel<<<1024, 256, 0, stream>>>(features, noise_lp, cands, nid, w64, q_buf);
    scatter_kernel<<<S_BLOCKS, 512, 0, stream>>>(features, q_buf, cands, partials);
    reduce_kernel<<<61, 256, 0, stream>>>(partials, out);
}